// Round 7
// baseline (120.833 us; speedup 1.0000x reference)
//
#include <hip/hip_runtime.h>
#include <hip/hip_bf16.h>

typedef __bf16 bf16x8 __attribute__((ext_vector_type(8)));
typedef float  f32x4  __attribute__((ext_vector_type(4)));

#define BS 64       // rotation block size
#define RB 64       // number of rotation blocks
#define NELEM 2016  // strict upper-triangle element count
#define DD 4096     // feature dim
#define MROWS 16384 // 4 * 4096 rows
#define TILES 8     // 16-row tiles per wave

// ---------------------------------------------------------------------------
// Kernel A (r6-verified row-split): R = I + 2Q + 2Q^2 + 2Q^3 + 2Q^4, emitted
// bf16 in packed fragment order:
//   Rpk[((rblk*8 + kf*4 + n)*64 + lane)*8 + jj] =
//       bf16( R[32*kf + 8*(lane>>4) + jj][16*n + (lane&15)] )
// Row-block recurrence: 4 blocks per rblk (256 blocks, full chip).
// ALL loops fully unrolled -> compile-time indices -> registers (rule #20).
// ---------------------------------------------------------------------------
__global__ __launch_bounds__(256) void rot_kernel(const float* __restrict__ w,
                                                  __bf16* __restrict__ Rpk) {
    const int bid   = blockIdx.x;
    const int blk   = bid >> 2;          // rblk
    const int rbase = (bid & 3) * 16;    // this block's 16 rows of R
    const int t     = threadIdx.x;
    __shared__ float Q [BS * BS];
    __shared__ float T0[16 * BS];
    __shared__ float T1[16 * BS];
    const float* wb = w + blk * NELEM;

    for (int e = t; e < BS * BS; e += 256) {
        const int i = e >> 6, j = e & 63;
        float v = 0.f;
        if (i < j)      v =  wb[63 * i - (i * (i - 1)) / 2 + (j - i - 1)];
        else if (i > j) v = -wb[63 * j - (j * (j - 1)) / 2 + (i - j - 1)];
        Q[e] = v;
    }
    __syncthreads();

    const int j  = t & 63;         // column
    const int s4 = (t >> 6) * 4;   // first of this thread's 4 rows (relative)

    float qcol[BS];
#pragma unroll
    for (int k = 0; k < BS; ++k) qcol[k] = Q[k * BS + j];

    float racc[4];
#pragma unroll
    for (int s = 0; s < 4; ++s) {
        const int i = rbase + s4 + s;
        racc[s] = (i == j ? 1.f : 0.f) + 2.f * Q[i * BS + j];
    }

#pragma unroll
    for (int s = 0; s < 4; ++s) {
        const int i = rbase + s4 + s;
        float sum = 0.f;
#pragma unroll
        for (int k = 0; k < BS; ++k) sum += Q[i * BS + k] * qcol[k];
        T0[(s4 + s) * BS + j] = sum;
        racc[s] += 2.f * sum;
    }
    __syncthreads();

#pragma unroll
    for (int s = 0; s < 4; ++s) {
        const int r = s4 + s;
        float sum = 0.f;
#pragma unroll
        for (int k = 0; k < BS; ++k) sum += T0[r * BS + k] * qcol[k];
        T1[r * BS + j] = sum;
        racc[s] += 2.f * sum;
    }
    __syncthreads();

#pragma unroll
    for (int s = 0; s < 4; ++s) {
        const int r = s4 + s;
        float sum = 0.f;
#pragma unroll
        for (int k = 0; k < BS; ++k) sum += T1[r * BS + k] * qcol[k];
        racc[s] += 2.f * sum;
    }

#pragma unroll
    for (int s = 0; s < 4; ++s) {
        const int i  = rbase + s4 + s;
        const int kf = i >> 5;
        const int g  = (i >> 3) & 3;
        const int jj = i & 7;
        const int lane = 16 * g + (j & 15);
        const int n    = j >> 4;
        Rpk[(size_t)((blk * 8 + kf * 4 + n) * 64 + lane) * 8 + jj] = (__bf16)racc[s];
    }
}

// ---------------------------------------------------------------------------
// Kernel B: y = x . R per 64-block via mfma_f32_16x16x32_bf16 (non-swapped,
// scalar nt stores — both measured-best). NEW vs r6: x is staged through a
// WAVE-PRIVATE 4KB LDS buffer with __builtin_amdgcn_global_load_lds:
//  - source lane mapping is row-major contiguous (instr q: rows 4q..4q+3,
//    full 64B lines, adjacent lanes adjacent) -> 64 line-touches/tile instead
//    of 256 for the direct A-frag-scatter loads (the r6 limiter: TA-bound,
//    all visible pipes <3% busy at 3.5 TB/s).
//  - XOR swizzle chunk' = chunk ^ row applied on the GLOBAL source (rule #21:
//    gload_lds dest must stay linear); XOR preserves 64B-line groups so
//    coalescing survives; ds_read_b128 of A-frags becomes ~uniform across
//    banks instead of 16-way conflicted.
//  - wave-private buffer -> NO barriers; ordering via counted vmcnt(16)
//    (stage(4) older than stores(16)) + lgkmcnt(0)+sched_barrier before
//    re-staging (rule #18).
// ---------------------------------------------------------------------------
__global__ __launch_bounds__(256) void apply_kernel(const float* __restrict__ x,
                                                    const __bf16* __restrict__ Rpk,
                                                    float* __restrict__ y) {
    __shared__ float xs[4][1024];        // 4KB per wave, wave-private
    const int tid  = threadIdx.x;
    const int l    = tid & 63;
    const int wv   = tid >> 6;
    const int W    = blockIdx.x * 4 + wv;
    const int rblk = W & 63;
    const int rg   = W >> 6;             // 0..127 row-groups of 128 rows
    const int g    = l >> 4;
    const int c    = l & 15;

    // Load the 8 B-fragments of R[rblk] (coalesced 16B per lane).
    bf16x8 bfrag[2][4];
    const bf16x8* rp = reinterpret_cast<const bf16x8*>(Rpk) + (size_t)rblk * 8 * 64 + l;
#pragma unroll
    for (int kf = 0; kf < 2; ++kf)
#pragma unroll
        for (int n = 0; n < 4; ++n)
            bfrag[kf][n] = rp[(kf * 4 + n) * 64];

    const long rowbase = (long)rg * (TILES * 16);

    // Per-lane stage sources: instr q covers tile rows 4q..4q+3; lane l ->
    // row 4q + (l>>4), source chunk = (l&15) ^ row (XOR swizzle, row < 16).
    const float* srcq[4];
#pragma unroll
    for (int q = 0; q < 4; ++q) {
        const int srow = 4 * q + (l >> 4);
        const int schk = (l & 15) ^ srow;
        srcq[q] = x + (rowbase + srow) * (long)DD + rblk * 64 + schk * 4;
    }
    float* const ldsb = &xs[wv][0];

#define STAGE(tt) do {                                                         \
    const long roff_ = (long)(tt) * 16 * DD;                                   \
    _Pragma("unroll")                                                          \
    for (int q_ = 0; q_ < 4; ++q_)                                             \
        __builtin_amdgcn_global_load_lds(                                      \
            (const __attribute__((address_space(1))) void*)(srcq[q_] + roff_), \
            (__attribute__((address_space(3))) void*)(ldsb + q_ * 256),        \
            16, 0, 0);                                                         \
} while (0)

    STAGE(0);
    asm volatile("s_waitcnt vmcnt(0)" ::: "memory");
    __builtin_amdgcn_sched_barrier(0);

#pragma unroll
    for (int t = 0; t < TILES; ++t) {
        // Read this lane's A-frag f32 pieces from swizzled LDS.
        // Row c (=l&15) at floats c*64; global chunk gc lives at chunk gc^c.
        f32x4 v0 = *reinterpret_cast<const f32x4*>(&xs[wv][c * 64 + (((2 * g + 0) ^ c) << 2)]);
        f32x4 v1 = *reinterpret_cast<const f32x4*>(&xs[wv][c * 64 + (((2 * g + 1) ^ c) << 2)]);
        f32x4 v2 = *reinterpret_cast<const f32x4*>(&xs[wv][c * 64 + (((8 + 2 * g + 0) ^ c) << 2)]);
        f32x4 v3 = *reinterpret_cast<const f32x4*>(&xs[wv][c * 64 + (((8 + 2 * g + 1) ^ c) << 2)]);

        // Convert to bf16 A-fragments (elem jj <-> k = 32kf + 8g + jj).
        bf16x8 a0, a1;
#pragma unroll
        for (int e = 0; e < 4; ++e) {
            a0[e]     = (__bf16)v0[e];
            a0[e + 4] = (__bf16)v1[e];
            a1[e]     = (__bf16)v2[e];
            a1[e + 4] = (__bf16)v3[e];
        }

        // All LDS reads retired before we overwrite the buffer (rule #18).
        asm volatile("s_waitcnt lgkmcnt(0)" ::: "memory");
        __builtin_amdgcn_sched_barrier(0);
        if (t + 1 < TILES) STAGE(t + 1);

        const f32x4 zero = {0.f, 0.f, 0.f, 0.f};
        f32x4 acc[4];
#pragma unroll
        for (int n = 0; n < 4; ++n)
            acc[n] = __builtin_amdgcn_mfma_f32_16x16x32_bf16(a0, bfrag[0][n], zero, 0, 0, 0);
#pragma unroll
        for (int n = 0; n < 4; ++n)
            acc[n] = __builtin_amdgcn_mfma_f32_16x16x32_bf16(a1, bfrag[1][n], acc[n], 0, 0, 0);

        // Store: lane holds rows 4g+i, col c+16n of this 16x64 tile.
        // Scalar nontemporal stores: 16 adjacent lanes -> full 64B lines
        // (measured-best; x4-swapped variant was 17us slower, r4/r5).
        float* yl = y + (rowbase + t * 16 + 4 * g) * (long)DD + rblk * 64 + c;
#pragma unroll
        for (int n = 0; n < 4; ++n)
#pragma unroll
            for (int i = 0; i < 4; ++i)
                __builtin_nontemporal_store(acc[n][i], yl + (long)i * DD + n * 16);

        // Wait for the 4 stage loads (older) to land; the 16 stores above
        // are the only younger vmem ops -> vmcnt(16).
        asm volatile("s_waitcnt vmcnt(16)" ::: "memory");
        __builtin_amdgcn_sched_barrier(0);
    }
#undef STAGE
}

extern "C" void kernel_launch(void* const* d_in, const int* in_sizes, int n_in,
                              void* d_out, int out_size, void* d_ws, size_t ws_size,
                              hipStream_t stream) {
    (void)in_sizes; (void)n_in; (void)out_size; (void)ws_size;
    const float* x = (const float*)d_in[0];
    const float* w = (const float*)d_in[1];
    float* y = (float*)d_out;
    __bf16* Rpk = (__bf16*)d_ws;   // 64 rblk * 8 frags * 64 lanes * 8 bf16 = 512 KB

    rot_kernel<<<RB * 4, 256, 0, stream>>>(w, Rpk);

    const int waves  = RB * (MROWS / (TILES * 16));  // 64 * 128 = 8192
    const int blocks = waves / 4;                    // 2048 blocks of 256 thr
    apply_kernel<<<blocks, 256, 0, stream>>>(x, Rpk, y);
}